// Round 4
// baseline (490.834 us; speedup 1.0000x reference)
//
#include <hip/hip_runtime.h>
#include <cstdint>
#include <cstddef>

#define DECAY 0.8f
#define OMD 0.2f            // 1 - decay
#define EPS_LAP 1e-5f
#define EPS_NORM 1e-6f
#define DELTA 3e-3f         // refinement margin (>4x estimated max bf16 dist error)

constexpr int ROWS  = 8192;   // b*n = 4*2048
constexpr int DIM   = 512;
constexpr int CODES = 8192;

// flat output offsets (floats), in reference return order
constexpr size_t OFF_Q    = 0;
constexpr size_t OFF_IND  = OFF_Q    + (size_t)ROWS * DIM;
constexpr size_t OFF_DIST = OFF_IND  + (size_t)ROWS;
constexpr size_t OFF_NCS  = OFF_DIST + (size_t)ROWS * CODES;
constexpr size_t OFF_NEA  = OFF_NCS  + (size_t)CODES;
constexpr size_t OFF_NE   = OFF_NEA  + (size_t)CODES * DIM;

typedef __bf16 bf16x8_t __attribute__((ext_vector_type(8)));
typedef float  f32x16_t __attribute__((ext_vector_type(16)));
typedef unsigned short u16x8_t __attribute__((ext_vector_type(8)));
typedef unsigned long long ull;

// ---------- helpers ----------

__device__ __forceinline__ unsigned int ford(float f) {
    unsigned int u = __float_as_uint(f);
    return (u & 0x80000000u) ? ~u : (u | 0x80000000u);
}
__device__ __forceinline__ float unford(unsigned int u) {
    unsigned int v = (u & 0x80000000u) ? (u & 0x7fffffffu) : ~u;
    return __uint_as_float(v);
}

__device__ inline float block_reduce_sum_256(float v, float* sm) {
    #pragma unroll
    for (int off = 32; off > 0; off >>= 1) v += __shfl_down(v, off, 64);
    __syncthreads();
    if ((threadIdx.x & 63) == 0) sm[threadIdx.x >> 6] = v;
    __syncthreads();
    return sm[0] + sm[1] + sm[2] + sm[3];
}

// direct global->LDS async copy, 16B per lane (global_load_lds_dwordx4)
#define GLOAD16(gp, lp) \
    __builtin_amdgcn_global_load_lds( \
        (const __attribute__((address_space(1))) void*)(gp), \
        (__attribute__((address_space(3))) void*)(lp), 16, 0, 0)

// ---------- packed operand layouts (verified round-1) ----------
// A_pack: row r, k-octet o: bm=r>>7, rt=(r&127)>>5, kc=o>>2, oc=o&3, s=oc>>1,
//   kg=oc&1, lane=(r&31)+32*kg; short idx = (((bm*16+kc)*4+rt)*2+s)*512 + lane*8
// B_pack: code c: bn=c>>8, ct=(c&255)>>5; short idx = (((bn*16+kc)*8+ct)*2+s)*512 + lane*8

// ---------- kernel 1: pack A/B bf16 + EMA init + sum(cs) ----------

__global__ __launch_bounds__(256) void prep(
    const float* __restrict__ x, const float* __restrict__ embed,
    const float* __restrict__ cs, const float* __restrict__ ea,
    unsigned short* __restrict__ Apk, unsigned short* __restrict__ Bpk,
    float* __restrict__ ncs, float* __restrict__ nea,
    float* __restrict__ sum_cs) {
    __shared__ float sm[4];
    const int t = threadIdx.x;
    const int bid = blockIdx.x;
    constexpr int NRB = (ROWS + CODES) / 4;          // 4096 pack blocks (wave/row)
    constexpr int NEB = (CODES * DIM / 4) / 256;     // 4096 ema blocks
    if (bid < NRB) {
        const int w = t >> 6, lane = t & 63;
        const int r = bid * 4 + w;
        const bool isA = r < ROWS;
        const float* rowp = isA ? x + (size_t)r * DIM
                                : embed + (size_t)(r - ROWS) * DIM;
        const float4 v0 = ((const float4*)rowp)[lane * 2];
        const float4 v1 = ((const float4*)rowp)[lane * 2 + 1];
        float sc = 1.0f;
        if (isA) {
            float ss = v0.x * v0.x + v0.y * v0.y + v0.z * v0.z + v0.w * v0.w
                     + v1.x * v1.x + v1.y * v1.y + v1.z * v1.z + v1.w * v1.w;
            #pragma unroll
            for (int o = 32; o > 0; o >>= 1) ss += __shfl_xor(ss, o, 64);
            sc = 1.0f / fmaxf(sqrtf(ss), EPS_NORM);
        }
        const float f[8] = {v0.x, v0.y, v0.z, v0.w, v1.x, v1.y, v1.z, v1.w};
        u16x8_t hv;
        #pragma unroll
        for (int j = 0; j < 8; j++) {
            __bf16 b = (__bf16)(f[j] * sc);
            hv[j] = *(unsigned short*)&b;
        }
        const int kc = lane >> 2, oc = lane & 3, s = oc >> 1, kg = oc & 1;
        size_t idx; unsigned short* dst;
        if (isA) {
            const int bm = r >> 7, rt = (r & 127) >> 5, ln = (r & 31) + 32 * kg;
            idx = ((((size_t)(bm * 16 + kc)) * 4 + rt) * 2 + s) * 512 + (size_t)ln * 8;
            dst = Apk;
        } else {
            const int c = r - ROWS;
            const int bn = c >> 8, ct = (c & 255) >> 5, ln = (c & 31) + 32 * kg;
            idx = ((((size_t)(bn * 16 + kc)) * 8 + ct) * 2 + s) * 512 + (size_t)ln * 8;
            dst = Bpk;
        }
        *(u16x8_t*)(dst + idx) = hv;
    } else if (bid < NRB + NEB) {
        // folded ema_init: ncs = decay*cs, nea = decay*ea
        const int gid = (bid - NRB) * 256 + t;       // over CODES*DIM/4 float4s
        float4 e = ((const float4*)ea)[gid];
        e.x *= DECAY; e.y *= DECAY; e.z *= DECAY; e.w *= DECAY;
        ((float4*)nea)[gid] = e;
        if (gid < CODES / 4) {
            float4 c = ((const float4*)cs)[gid];
            c.x *= DECAY; c.y *= DECAY; c.z *= DECAY; c.w *= DECAY;
            ((float4*)ncs)[gid] = c;
        }
    } else {
        // sum(cs) for embed_norm's analytic denom
        float local = 0.f;
        #pragma unroll
        for (int i = 0; i < CODES / 256; i++) local += cs[t + i * 256];
        const float tot = block_reduce_sum_256(local, sm);
        if (t == 0) *sum_cs = tot;
    }
}

// ---------- kernel 2: bf16 MFMA GEMM dist = xn @ embed^T + blockkey epilogue ----------
// Block tile 128x256, 4 waves (2x2), wave = 64x128 = 2x4 of 32x32x16.
// TRIPLE-buffered LDS fed by global_load_lds dwordx4, counted vmcnt(6) (T3+T4):
// per K-step: [wait vmcnt(6); s_barrier; issue tile k+2; MFMA cluster].
// Loads for the next-next tile stay in flight across the barrier (never drain to 0).
// Safety: reuse distance 3 > issue distance 2, issue after barrier => all waves
// have finished computing the buffer being overwritten (one barrier per step).

__global__ __launch_bounds__(256, 2) void gemm_bf16(
    const unsigned short* __restrict__ Apk, const unsigned short* __restrict__ Bpk,
    float* __restrict__ D, ull* __restrict__ blockkey) {
    __shared__ __align__(16) unsigned short A_s[3][4096];   // 24KB
    __shared__ __align__(16) unsigned short B_s[3][8192];   // 48KB
    __shared__ ull rowkey[128];                             // 1KB
    const int t = threadIdx.x;
    const int bn = blockIdx.x, bm = blockIdx.y;
    const int lane = t & 63, w = t >> 6;
    const int wm = w >> 1, wn = w & 1;
    const int lr = lane & 31, kg = lane >> 5;

    if (t < 128) rowkey[t] = 0ull;

    const unsigned short* gA = Apk + (size_t)bm * (16 * 4096) + t * 8;
    const unsigned short* gB = Bpk + (size_t)bn * (16 * 8192) + t * 8;

    f32x16_t acc[2][4];
    #pragma unroll
    for (int i = 0; i < 2; i++)
        #pragma unroll
        for (int j = 0; j < 4; j++)
            #pragma unroll
            for (int r = 0; r < 16; r++) acc[i][j][r] = 0.f;

    // stage tile -> buffer (6 x global_load_lds_dwordx4 per thread-slot)
    auto stage = [&](int tile, int buf) {
        const unsigned short* a = gA + tile * 4096;
        const unsigned short* b = gB + (size_t)tile * 8192;
        unsigned short* As = &A_s[buf][t * 8];
        unsigned short* Bs = &B_s[buf][t * 8];
        GLOAD16(a,        As);
        GLOAD16(a + 2048, As + 2048);
        GLOAD16(b,        Bs);
        GLOAD16(b + 2048, Bs + 2048);
        GLOAD16(b + 4096, Bs + 4096);
        GLOAD16(b + 6144, Bs + 6144);
    };

    // prologue: two tiles in flight
    stage(0, 0);
    stage(1, 1);

    const int lo = lane * 8;
    int cur = 0, stg = 2;
    for (int kc = 0; kc < 16; kc++) {
        // wait for tile kc's 6 loads (leave the newer tile's 6 in flight)
        if (kc < 15) asm volatile("s_waitcnt vmcnt(6)" ::: "memory");
        else         asm volatile("s_waitcnt vmcnt(0)" ::: "memory");
        asm volatile("s_barrier" ::: "memory");
        if (kc + 2 < 16) stage(kc + 2, stg);   // issue under the MFMA cluster

        const unsigned short* Ab = &A_s[cur][0];
        const unsigned short* Bb = &B_s[cur][0];
        __builtin_amdgcn_s_setprio(1);
        #pragma unroll
        for (int s = 0; s < 2; s++) {
            bf16x8_t a0 = *(const bf16x8_t*)&Ab[(4 * wm + s) * 512 + lo];
            bf16x8_t a1 = *(const bf16x8_t*)&Ab[(4 * wm + 2 + s) * 512 + lo];
            bf16x8_t b0 = *(const bf16x8_t*)&Bb[(8 * wn + s) * 512 + lo];
            bf16x8_t b1 = *(const bf16x8_t*)&Bb[(8 * wn + 2 + s) * 512 + lo];
            bf16x8_t b2 = *(const bf16x8_t*)&Bb[(8 * wn + 4 + s) * 512 + lo];
            bf16x8_t b3 = *(const bf16x8_t*)&Bb[(8 * wn + 6 + s) * 512 + lo];
            acc[0][0] = __builtin_amdgcn_mfma_f32_32x32x16_bf16(a0, b0, acc[0][0], 0, 0, 0);
            acc[0][1] = __builtin_amdgcn_mfma_f32_32x32x16_bf16(a0, b1, acc[0][1], 0, 0, 0);
            acc[0][2] = __builtin_amdgcn_mfma_f32_32x32x16_bf16(a0, b2, acc[0][2], 0, 0, 0);
            acc[0][3] = __builtin_amdgcn_mfma_f32_32x32x16_bf16(a0, b3, acc[0][3], 0, 0, 0);
            acc[1][0] = __builtin_amdgcn_mfma_f32_32x32x16_bf16(a1, b0, acc[1][0], 0, 0, 0);
            acc[1][1] = __builtin_amdgcn_mfma_f32_32x32x16_bf16(a1, b1, acc[1][1], 0, 0, 0);
            acc[1][2] = __builtin_amdgcn_mfma_f32_32x32x16_bf16(a1, b2, acc[1][2], 0, 0, 0);
            acc[1][3] = __builtin_amdgcn_mfma_f32_32x32x16_bf16(a1, b3, acc[1][3], 0, 0, 0);
        }
        __builtin_amdgcn_s_setprio(0);
        cur = (cur == 2) ? 0 : cur + 1;
        stg = (stg == 2) ? 0 : stg + 1;
    }

    // epilogue: coalesced D stores + per-row key (width-32 shuffle + LDS merge)
    const int colb = bn * 256 + wn * 128 + lr;
    #pragma unroll
    for (int mt = 0; mt < 2; mt++) {
        #pragma unroll
        for (int reg = 0; reg < 16; reg++) {
            const int rloc = wm * 64 + mt * 32 + (reg & 3) + 8 * (reg >> 2) + 4 * kg;
            float* dpp = D + (size_t)(bm * 128 + rloc) * CODES + colb;
            ull key = 0ull;
            #pragma unroll
            for (int ct = 0; ct < 4; ct++) {
                const float v = acc[mt][ct][reg];
                dpp[ct * 32] = v;
                ull k2 = ((ull)ford(v) << 32)
                       | (unsigned)(CODES - 1 - (colb + ct * 32));
                if (k2 > key) key = k2;
            }
            #pragma unroll
            for (int m = 1; m <= 16; m <<= 1) {
                ull o = __shfl_xor(key, m, 32);
                if (o > key) key = o;
            }
            if (lr == 0) atomicMax(&rowkey[rloc], key);
        }
    }
    __syncthreads();
    if (t < 128)
        blockkey[(size_t)(bm * 128 + t) * 32 + bn] = rowkey[t];
}

// ---------- kernel 3: select + fp32 refine + finalize (block per row) ----------
// Reads 32 block keys (256B/row) instead of the 32KB dist row; scans only the
// dist segments whose block max reaches thr (usually exactly one 1KB segment).

__global__ __launch_bounds__(256) void select_rows(
    const ull* __restrict__ blockkey, const float* __restrict__ D,
    const float* __restrict__ x, const float* __restrict__ embed,
    float* __restrict__ q, float* __restrict__ indf,
    float* __restrict__ ncs, float* __restrict__ nea) {
    const int row = blockIdx.x, t = threadIdx.x;
    const int lane = t & 63, w = t >> 6;
    __shared__ float sbv[32];
    __shared__ ull  redk[4];
    __shared__ float redf[4];
    __shared__ ull  skey;
    __shared__ int  cnt;
    __shared__ int  cand[64];
    __shared__ float cx[DIM];

    ull bk = 0ull;
    if (t < 32) {
        bk = blockkey[(size_t)row * 32 + t];
        sbv[t] = unford((unsigned)(bk >> 32));
    }
    if (t == 0) cnt = 0;
    const float2 xv = ((const float2*)(x + (size_t)row * DIM))[t];
    float ss = xv.x * xv.x + xv.y * xv.y;
    #pragma unroll
    for (int o = 32; o > 0; o >>= 1) ss += __shfl_xor(ss, o, 64);
    if (lane == 0) redf[w] = ss;
    if (w == 0) {
        #pragma unroll
        for (int m = 1; m <= 32; m <<= 1) {
            ull o = __shfl_xor(bk, m, 64);
            if (o > bk) bk = o;
        }
        if (t == 0) skey = bk;
    }
    __syncthreads();
    const float nx = fmaxf(sqrtf(redf[0] + redf[1] + redf[2] + redf[3]), EPS_NORM);
    const ull key = skey;
    const float thr = unford((unsigned)(key >> 32)) - DELTA;

    // candidate scan: only blocks whose max reaches thr
    for (int b = 0; b < 32; b++) {
        if (sbv[b] >= thr) {
            const float v = D[(size_t)row * CODES + b * 256 + t];
            if (v >= thr) {
                const int p = atomicAdd(&cnt, 1);
                if (p < 64) cand[p] = b * 256 + t;
            }
        }
    }
    __syncthreads();
    int best = CODES - 1 - (int)(key & 0xffffffffull);
    const int n = min(cnt, 64);
    if (n > 1) {                 // rare: exact fp32 recheck of the DELTA band
        cx[2 * t] = xv.x / nx; cx[2 * t + 1] = xv.y / nx;
        __syncthreads();
        ull bkey = 0ull;
        if (t < n) {
            const int c = cand[t];
            const float* e = embed + (size_t)c * DIM;
            float acc = 0.f;
            for (int k = 0; k < DIM; k++) acc = fmaf(cx[k], e[k], acc);
            bkey = ((ull)ford(acc) << 32) | (unsigned)(CODES - 1 - c);
        }
        #pragma unroll
        for (int m = 1; m <= 32; m <<= 1) {
            ull o = __shfl_xor(bkey, m, 64);
            if (o > bkey) bkey = o;
        }
        if (lane == 0) redk[w] = bkey;
        __syncthreads();
        ull fk = redk[0];
        #pragma unroll
        for (int i = 1; i < 4; i++) if (redk[i] > fk) fk = redk[i];
        best = CODES - 1 - (int)(fk & 0xffffffffull);
    }

    // finalize: quantize gather + EMA scatter
    const int c = best;
    const float2 ev = ((const float2*)(embed + (size_t)c * DIM))[t];
    ((float2*)(q + (size_t)row * DIM))[t] = ev;
    float* dstp = nea + (size_t)c * DIM + 2 * t;
    atomicAdd(dstp,     OMD * (xv.x / nx));
    atomicAdd(dstp + 1, OMD * (xv.y / nx));
    if (t == 0) { atomicAdd(&ncs[c], OMD); indf[row] = (float)c; }
}

// ---------- kernel 4: new_embed = l2norm(new_embed_avg / smoothed) ----------
// denom computed analytically: sum(ncs) = DECAY*sum(cs) + OMD*ROWS

__global__ __launch_bounds__(256) void embed_norm(
    const float* __restrict__ ncs, const float* __restrict__ nea,
    const float* __restrict__ sum_cs, float* __restrict__ ne) {
    __shared__ float sm[4];
    const int c = blockIdx.x;
    const int t = threadIdx.x;
    const float denom = DECAY * (*sum_cs) + OMD * (float)ROWS;
    const float s = (ncs[c] + EPS_LAP) / (denom + (float)CODES * EPS_LAP) * denom;
    const float2 v = ((const float2*)(nea + (size_t)c * DIM))[t];
    float2 wv;
    wv.x = v.x / s;
    wv.y = v.y / s;
    const float total = block_reduce_sum_256(wv.x * wv.x + wv.y * wv.y, sm);
    const float norm = fmaxf(sqrtf(total), EPS_NORM);
    float2 o;
    o.x = wv.x / norm;
    o.y = wv.y / norm;
    ((float2*)(ne + (size_t)c * DIM))[t] = o;
}

// ---------- host ----------

extern "C" void kernel_launch(void* const* d_in, const int* in_sizes, int n_in,
                              void* d_out, int out_size, void* d_ws, size_t ws_size,
                              hipStream_t stream) {
    const float* x     = (const float*)d_in[0];
    const float* embed = (const float*)d_in[1];
    const float* cs    = (const float*)d_in[2];
    const float* ea    = (const float*)d_in[3];

    float* out  = (float*)d_out;
    float* q    = out + OFF_Q;
    float* indf = out + OFF_IND;
    float* dist = out + OFF_DIST;
    float* ncs  = out + OFF_NCS;
    float* nea  = out + OFF_NEA;
    float* ne   = out + OFF_NE;

    // scratch aliased into later-written output regions:
    // A_pack (8.39MB) in ne[0 .. 8.39MB)       (ne written last by embed_norm)
    // blockkey (2MB)  in ne[8.39MB .. 10.4MB)
    // sum_cs (4B)     in ne[10.4MB ..)
    // B_pack (8.39MB) in q (q written by select_rows, after the GEMM)
    unsigned short* Apk = (unsigned short*)ne;
    unsigned short* Bpk = (unsigned short*)q;
    ull* blockkey = (ull*)(ne + (size_t)ROWS * DIM / 2);
    float* sum_cs = (float*)(blockkey + (size_t)ROWS * 32);

    constexpr int NRB = (ROWS + CODES) / 4;
    constexpr int NEB = (CODES * DIM / 4) / 256;
    hipLaunchKernelGGL(prep, dim3(NRB + NEB + 1), dim3(256), 0, stream,
                       x, embed, cs, ea, Apk, Bpk, ncs, nea, sum_cs);
    hipLaunchKernelGGL(gemm_bf16, dim3(CODES / 256, ROWS / 128), dim3(256), 0, stream,
                       Apk, Bpk, dist, blockkey);
    hipLaunchKernelGGL(select_rows, dim3(ROWS), dim3(256), 0, stream,
                       blockkey, dist, x, embed, q, indf, ncs, nea);
    hipLaunchKernelGGL(embed_norm, dim3(CODES), dim3(256), 0, stream,
                       ncs, nea, sum_cs, ne);
}

// Round 5
// 483.157 us; speedup vs baseline: 1.0159x; 1.0159x over previous
//
#include <hip/hip_runtime.h>
#include <cstdint>
#include <cstddef>

#define DECAY 0.8f
#define OMD 0.2f            // 1 - decay
#define EPS_LAP 1e-5f
#define EPS_NORM 1e-6f
#define DELTA 3e-3f         // refinement margin (>4x estimated max bf16 dist error)

constexpr int ROWS  = 8192;   // b*n = 4*2048
constexpr int DIM   = 512;
constexpr int CODES = 8192;

// flat output offsets (floats), in reference return order
constexpr size_t OFF_Q    = 0;
constexpr size_t OFF_IND  = OFF_Q    + (size_t)ROWS * DIM;
constexpr size_t OFF_DIST = OFF_IND  + (size_t)ROWS;
constexpr size_t OFF_NCS  = OFF_DIST + (size_t)ROWS * CODES;
constexpr size_t OFF_NEA  = OFF_NCS  + (size_t)CODES;
constexpr size_t OFF_NE   = OFF_NEA  + (size_t)CODES * DIM;

typedef __bf16 bf16x8_t __attribute__((ext_vector_type(8)));
typedef float  f32x16_t __attribute__((ext_vector_type(16)));
typedef unsigned short u16x8_t __attribute__((ext_vector_type(8)));
typedef unsigned long long ull;

// ---------- helpers ----------

__device__ __forceinline__ unsigned int ford(float f) {
    unsigned int u = __float_as_uint(f);
    return (u & 0x80000000u) ? ~u : (u | 0x80000000u);
}
__device__ __forceinline__ float unford(unsigned int u) {
    unsigned int v = (u & 0x80000000u) ? (u & 0x7fffffffu) : ~u;
    return __uint_as_float(v);
}

__device__ inline float block_reduce_sum_256(float v, float* sm) {
    #pragma unroll
    for (int off = 32; off > 0; off >>= 1) v += __shfl_down(v, off, 64);
    __syncthreads();
    if ((threadIdx.x & 63) == 0) sm[threadIdx.x >> 6] = v;
    __syncthreads();
    return sm[0] + sm[1] + sm[2] + sm[3];
}

// direct global->LDS async copy, 16B per lane (global_load_lds_dwordx4)
#define GLOAD16(gp, lp) \
    __builtin_amdgcn_global_load_lds( \
        (const __attribute__((address_space(1))) void*)(gp), \
        (__attribute__((address_space(3))) void*)(lp), 16, 0, 0)

// ---------- packed operand layouts (verified round-1; bytes unchanged) ----------
// octet o (8 bf16) of row r maps to chunk (kc=o>>2, s=(o>>1)&1, kg=o&1), lane
// ln = (r&31) + 32*kg. A chunk base = (((bm*16+kc)*4+rt)*2+s)*512, rt=(r&127)>>5.
// B chunk base = (((bn*16+kc)*8+ct)*2+s)*512, ct=(c&255)>>5.
// => every MFMA fragment is 64 lanes x contiguous 16B IN GLOBAL MEMORY: frag
//    loads are perfectly-coalesced global_load_dwordx4 (B skips LDS entirely).

// ---------- kernel 1: pack A/B bf16 (LDS-transposed, coalesced) + EMA init ----------
// Pack blocks: 64 rows staged to LDS (XOR-swizzled 16B granules), then each
// 1KB output chunk written as one fully-coalesced wave store.

__global__ __launch_bounds__(256) void prep(
    const float* __restrict__ x, const float* __restrict__ embed,
    const float* __restrict__ cs, const float* __restrict__ ea,
    unsigned short* __restrict__ Apk, unsigned short* __restrict__ Bpk,
    float* __restrict__ ncs, float* __restrict__ nea,
    float* __restrict__ sum_cs) {
    __shared__ __align__(16) unsigned short L[64 * 512];   // 64KB
    __shared__ float sm[4];
    const int t = threadIdx.x;
    const int bid = blockIdx.x;
    constexpr int NA  = ROWS / 64;                   // 128 A-pack blocks
    constexpr int NB  = CODES / 64;                  // 128 B-pack blocks
    constexpr int NEB = (CODES * DIM / 4) / 256;     // 4096 ema blocks
    if (bid < NA + NB) {
        const int w = t >> 6, lane = t & 63;
        const bool isA = bid < NA;
        const int pb = isA ? bid : bid - NA;         // pack-block index
        const float* srcbase = isA ? x : embed;
        // ---- stage: 4 waves x 16 rows -> LDS (swizzled granules) ----
        #pragma unroll
        for (int i = 0; i < 16; i++) {
            const int rl = w * 16 + i;               // row_local 0..63
            const float* rowp = srcbase + (size_t)(pb * 64 + rl) * DIM;
            const float4 v0 = ((const float4*)rowp)[lane * 2];
            const float4 v1 = ((const float4*)rowp)[lane * 2 + 1];
            float sc = 1.0f;
            if (isA) {
                float ss = v0.x * v0.x + v0.y * v0.y + v0.z * v0.z + v0.w * v0.w
                         + v1.x * v1.x + v1.y * v1.y + v1.z * v1.z + v1.w * v1.w;
                #pragma unroll
                for (int o = 32; o > 0; o >>= 1) ss += __shfl_xor(ss, o, 64);
                sc = 1.0f / fmaxf(sqrtf(ss), EPS_NORM);
            }
            const float f[8] = {v0.x, v0.y, v0.z, v0.w, v1.x, v1.y, v1.z, v1.w};
            u16x8_t hv;
            #pragma unroll
            for (int j = 0; j < 8; j++) {
                __bf16 b = (__bf16)(f[j] * sc);
                hv[j] = *(unsigned short*)&b;
            }
            const int p = lane ^ (rl & 7);           // granule swizzle (G4)
            *(u16x8_t*)&L[rl * 512 + p * 8] = hv;
        }
        __syncthreads();
        // ---- write-out: 64 chunks of 1KB, each one coalesced wave store ----
        #pragma unroll
        for (int i = 0; i < 16; i++) {
            const int ch = w * 16 + i;
            const int kc = ch >> 2, half = (ch >> 1) & 1, s = ch & 1;
            const int rl = half * 32 + (lane & 31);  // row_local
            const int o  = kc * 4 + s * 2 + (lane >> 5);
            const u16x8_t hv = *(const u16x8_t*)&L[rl * 512 + (o ^ (rl & 7)) * 8];
            size_t base;
            unsigned short* dst;
            if (isA) {
                const int bm = pb >> 1, rt = (pb & 1) * 2 + half;
                base = ((((size_t)(bm * 16 + kc)) * 4 + rt) * 2 + s) * 512;
                dst = Apk;
            } else {
                const int bn = pb >> 2, ct = (pb & 3) * 2 + half;
                base = ((((size_t)(bn * 16 + kc)) * 8 + ct) * 2 + s) * 512;
                dst = Bpk;
            }
            *(u16x8_t*)(dst + base + (size_t)lane * 8) = hv;
        }
    } else if (bid < NA + NB + NEB) {
        // folded ema_init: ncs = decay*cs, nea = decay*ea
        const int gid = (bid - NA - NB) * 256 + t;   // over CODES*DIM/4 float4s
        float4 e = ((const float4*)ea)[gid];
        e.x *= DECAY; e.y *= DECAY; e.z *= DECAY; e.w *= DECAY;
        ((float4*)nea)[gid] = e;
        if (gid < CODES / 4) {
            float4 c = ((const float4*)cs)[gid];
            c.x *= DECAY; c.y *= DECAY; c.z *= DECAY; c.w *= DECAY;
            ((float4*)ncs)[gid] = c;
        }
    } else {
        // sum(cs) for embed_norm's analytic denom
        float local = 0.f;
        #pragma unroll
        for (int i = 0; i < CODES / 256; i++) local += cs[t + i * 256];
        const float tot = block_reduce_sum_256(local, sm);
        if (t == 0) *sum_cs = tot;
    }
}

// ---------- kernel 2: bf16 MFMA GEMM dist = xn @ embed^T + blockkey epilogue ----------
// Block tile 128x256, 4 waves (2x2), wave = 64x128 = 2x4 of 32x32x16.
// A: LDS double-buffer via global_load_lds (round-3 verified structure).
// B: DIRECT global->VGPR fragment loads (coalesced 16B/lane), prefetched one
//    K-step ahead. Removes 8 of 12 ds_reads and 2/3 of LDS writes per K-step
//    (LDS-port-bound diagnosis from round-4 null).

__global__ __launch_bounds__(256, 2) void gemm_bf16(
    const unsigned short* __restrict__ Apk, const unsigned short* __restrict__ Bpk,
    float* __restrict__ D, ull* __restrict__ blockkey) {
    __shared__ __align__(16) unsigned short A_s[2][4096];   // 16KB
    __shared__ ull rowkey[128];                             // 1KB
    const int t = threadIdx.x;
    const int bn = blockIdx.x, bm = blockIdx.y;
    const int lane = t & 63, w = t >> 6;
    const int wm = w >> 1, wn = w & 1;
    const int lr = lane & 31, kg = lane >> 5;

    if (t < 128) rowkey[t] = 0ull;

    const unsigned short* gA = Apk + (size_t)bm * (16 * 4096) + t * 8;
    // per-wave B fragment base: frag(kc,ctl,s) = gBf + kc*8192 + ctl*1024 + s*512
    const unsigned short* gBf = Bpk + (size_t)bn * (16 * 8192) + wn * 4096 + lane * 8;

    f32x16_t acc[2][4];
    #pragma unroll
    for (int i = 0; i < 2; i++)
        #pragma unroll
        for (int j = 0; j < 4; j++)
            #pragma unroll
            for (int r = 0; r < 16; r++) acc[i][j][r] = 0.f;

    bf16x8_t breg[2][8];   // [kc&1][ctl*2+s] — all indices static (full unroll)

    // prologue: stage A(0), load B(0)
    GLOAD16(gA,        &A_s[0][t * 8]);
    GLOAD16(gA + 2048, &A_s[0][t * 8 + 2048]);
    #pragma unroll
    for (int f = 0; f < 8; f++)
        breg[0][f] = *(const bf16x8_t*)(gBf + (f >> 1) * 1024 + (f & 1) * 512);
    __syncthreads();

    const int lo = lane * 8;
    #pragma unroll
    for (int kc = 0; kc < 16; kc++) {
        const int cur = kc & 1;
        if (kc < 15) {
            GLOAD16(gA + (kc + 1) * 4096,        &A_s[cur ^ 1][t * 8]);
            GLOAD16(gA + (kc + 1) * 4096 + 2048, &A_s[cur ^ 1][t * 8 + 2048]);
            const unsigned short* bp = gBf + (size_t)(kc + 1) * 8192;
            #pragma unroll
            for (int f = 0; f < 8; f++)
                breg[cur ^ 1][f] = *(const bf16x8_t*)(bp + (f >> 1) * 1024 + (f & 1) * 512);
        }
        #pragma unroll
        for (int s = 0; s < 2; s++) {
            bf16x8_t a0 = *(const bf16x8_t*)&A_s[cur][(4 * wm + s) * 512 + lo];
            bf16x8_t a1 = *(const bf16x8_t*)&A_s[cur][(4 * wm + 2 + s) * 512 + lo];
            acc[0][0] = __builtin_amdgcn_mfma_f32_32x32x16_bf16(a0, breg[cur][0 * 2 + s], acc[0][0], 0, 0, 0);
            acc[0][1] = __builtin_amdgcn_mfma_f32_32x32x16_bf16(a0, breg[cur][1 * 2 + s], acc[0][1], 0, 0, 0);
            acc[0][2] = __builtin_amdgcn_mfma_f32_32x32x16_bf16(a0, breg[cur][2 * 2 + s], acc[0][2], 0, 0, 0);
            acc[0][3] = __builtin_amdgcn_mfma_f32_32x32x16_bf16(a0, breg[cur][3 * 2 + s], acc[0][3], 0, 0, 0);
            acc[1][0] = __builtin_amdgcn_mfma_f32_32x32x16_bf16(a1, breg[cur][0 * 2 + s], acc[1][0], 0, 0, 0);
            acc[1][1] = __builtin_amdgcn_mfma_f32_32x32x16_bf16(a1, breg[cur][1 * 2 + s], acc[1][1], 0, 0, 0);
            acc[1][2] = __builtin_amdgcn_mfma_f32_32x32x16_bf16(a1, breg[cur][2 * 2 + s], acc[1][2], 0, 0, 0);
            acc[1][3] = __builtin_amdgcn_mfma_f32_32x32x16_bf16(a1, breg[cur][3 * 2 + s], acc[1][3], 0, 0, 0);
        }
        __syncthreads();   // A(kc+1) staged & visible; B prefetch unaffected (regs)
    }

    // epilogue: coalesced D stores + per-row key (width-32 shuffle + LDS merge)
    const int colb = bn * 256 + wn * 128 + lr;
    #pragma unroll
    for (int mt = 0; mt < 2; mt++) {
        #pragma unroll
        for (int reg = 0; reg < 16; reg++) {
            const int rloc = wm * 64 + mt * 32 + (reg & 3) + 8 * (reg >> 2) + 4 * kg;
            float* dpp = D + (size_t)(bm * 128 + rloc) * CODES + colb;
            ull key = 0ull;
            #pragma unroll
            for (int ct = 0; ct < 4; ct++) {
                const float v = acc[mt][ct][reg];
                dpp[ct * 32] = v;
                ull k2 = ((ull)ford(v) << 32)
                       | (unsigned)(CODES - 1 - (colb + ct * 32));
                if (k2 > key) key = k2;
            }
            #pragma unroll
            for (int m = 1; m <= 16; m <<= 1) {
                ull o = __shfl_xor(key, m, 32);
                if (o > key) key = o;
            }
            if (lr == 0) atomicMax(&rowkey[rloc], key);
        }
    }
    __syncthreads();
    if (t < 128)
        blockkey[(size_t)(bm * 128 + t) * 32 + bn] = rowkey[t];
}

// ---------- kernel 3: select + fp32 refine + finalize (block per row) ----------

__global__ __launch_bounds__(256) void select_rows(
    const ull* __restrict__ blockkey, const float* __restrict__ D,
    const float* __restrict__ x, const float* __restrict__ embed,
    float* __restrict__ q, float* __restrict__ indf,
    float* __restrict__ ncs, float* __restrict__ nea) {
    const int row = blockIdx.x, t = threadIdx.x;
    const int lane = t & 63, w = t >> 6;
    __shared__ float sbv[32];
    __shared__ ull  redk[4];
    __shared__ float redf[4];
    __shared__ ull  skey;
    __shared__ int  cnt;
    __shared__ int  cand[64];
    __shared__ float cx[DIM];

    ull bk = 0ull;
    if (t < 32) {
        bk = blockkey[(size_t)row * 32 + t];
        sbv[t] = unford((unsigned)(bk >> 32));
    }
    if (t == 0) cnt = 0;
    const float2 xv = ((const float2*)(x + (size_t)row * DIM))[t];
    float ss = xv.x * xv.x + xv.y * xv.y;
    #pragma unroll
    for (int o = 32; o > 0; o >>= 1) ss += __shfl_xor(ss, o, 64);
    if (lane == 0) redf[w] = ss;
    if (w == 0) {
        #pragma unroll
        for (int m = 1; m <= 32; m <<= 1) {
            ull o = __shfl_xor(bk, m, 64);
            if (o > bk) bk = o;
        }
        if (t == 0) skey = bk;
    }
    __syncthreads();
    const float nx = fmaxf(sqrtf(redf[0] + redf[1] + redf[2] + redf[3]), EPS_NORM);
    const ull key = skey;
    const float thr = unford((unsigned)(key >> 32)) - DELTA;

    // candidate scan: only blocks whose max reaches thr
    for (int b = 0; b < 32; b++) {
        if (sbv[b] >= thr) {
            const float v = D[(size_t)row * CODES + b * 256 + t];
            if (v >= thr) {
                const int p = atomicAdd(&cnt, 1);
                if (p < 64) cand[p] = b * 256 + t;
            }
        }
    }
    __syncthreads();
    int best = CODES - 1 - (int)(key & 0xffffffffull);
    const int n = min(cnt, 64);
    if (n > 1) {                 // rare: exact fp32 recheck of the DELTA band
        cx[2 * t] = xv.x / nx; cx[2 * t + 1] = xv.y / nx;
        __syncthreads();
        ull bkey = 0ull;
        if (t < n) {
            const int c = cand[t];
            const float* e = embed + (size_t)c * DIM;
            float acc = 0.f;
            for (int k = 0; k < DIM; k++) acc = fmaf(cx[k], e[k], acc);
            bkey = ((ull)ford(acc) << 32) | (unsigned)(CODES - 1 - c);
        }
        #pragma unroll
        for (int m = 1; m <= 32; m <<= 1) {
            ull o = __shfl_xor(bkey, m, 64);
            if (o > bkey) bkey = o;
        }
        if (lane == 0) redk[w] = bkey;
        __syncthreads();
        ull fk = redk[0];
        #pragma unroll
        for (int i = 1; i < 4; i++) if (redk[i] > fk) fk = redk[i];
        best = CODES - 1 - (int)(fk & 0xffffffffull);
    }

    // finalize: quantize gather + EMA scatter
    const int c = best;
    const float2 ev = ((const float2*)(embed + (size_t)c * DIM))[t];
    ((float2*)(q + (size_t)row * DIM))[t] = ev;
    float* dstp = nea + (size_t)c * DIM + 2 * t;
    atomicAdd(dstp,     OMD * (xv.x / nx));
    atomicAdd(dstp + 1, OMD * (xv.y / nx));
    if (t == 0) { atomicAdd(&ncs[c], OMD); indf[row] = (float)c; }
}

// ---------- kernel 4: new_embed = l2norm(new_embed_avg / smoothed) ----------
// denom computed analytically: sum(ncs) = DECAY*sum(cs) + OMD*ROWS

__global__ __launch_bounds__(256) void embed_norm(
    const float* __restrict__ ncs, const float* __restrict__ nea,
    const float* __restrict__ sum_cs, float* __restrict__ ne) {
    __shared__ float sm[4];
    const int c = blockIdx.x;
    const int t = threadIdx.x;
    const float denom = DECAY * (*sum_cs) + OMD * (float)ROWS;
    const float s = (ncs[c] + EPS_LAP) / (denom + (float)CODES * EPS_LAP) * denom;
    const float2 v = ((const float2*)(nea + (size_t)c * DIM))[t];
    float2 wv;
    wv.x = v.x / s;
    wv.y = v.y / s;
    const float total = block_reduce_sum_256(wv.x * wv.x + wv.y * wv.y, sm);
    const float norm = fmaxf(sqrtf(total), EPS_NORM);
    float2 o;
    o.x = wv.x / norm;
    o.y = wv.y / norm;
    ((float2*)(ne + (size_t)c * DIM))[t] = o;
}

// ---------- host ----------

extern "C" void kernel_launch(void* const* d_in, const int* in_sizes, int n_in,
                              void* d_out, int out_size, void* d_ws, size_t ws_size,
                              hipStream_t stream) {
    const float* x     = (const float*)d_in[0];
    const float* embed = (const float*)d_in[1];
    const float* cs    = (const float*)d_in[2];
    const float* ea    = (const float*)d_in[3];

    float* out  = (float*)d_out;
    float* q    = out + OFF_Q;
    float* indf = out + OFF_IND;
    float* dist = out + OFF_DIST;
    float* ncs  = out + OFF_NCS;
    float* nea  = out + OFF_NEA;
    float* ne   = out + OFF_NE;

    // scratch aliased into later-written output regions:
    // A_pack (8.39MB) in ne[0 .. 8.39MB)       (ne written last by embed_norm)
    // blockkey (2MB)  in ne[8.39MB .. 10.4MB)
    // sum_cs (4B)     in ne[10.4MB ..)
    // B_pack (8.39MB) in q (q written by select_rows, after the GEMM)
    unsigned short* Apk = (unsigned short*)ne;
    unsigned short* Bpk = (unsigned short*)q;
    ull* blockkey = (ull*)(ne + (size_t)ROWS * DIM / 2);
    float* sum_cs = (float*)(blockkey + (size_t)ROWS * 32);

    constexpr int NA  = ROWS / 64;
    constexpr int NB  = CODES / 64;
    constexpr int NEB = (CODES * DIM / 4) / 256;
    hipLaunchKernelGGL(prep, dim3(NA + NB + NEB + 1), dim3(256), 0, stream,
                       x, embed, cs, ea, Apk, Bpk, ncs, nea, sum_cs);
    hipLaunchKernelGGL(gemm_bf16, dim3(CODES / 256, ROWS / 128), dim3(256), 0, stream,
                       Apk, Bpk, dist, blockkey);
    hipLaunchKernelGGL(select_rows, dim3(ROWS), dim3(256), 0, stream,
                       blockkey, dist, x, embed, q, indf, ncs, nea);
    hipLaunchKernelGGL(embed_norm, dim3(CODES), dim3(256), 0, stream,
                       ncs, nea, sum_cs, ne);
}